// Round 4
// baseline (244.247 us; speedup 1.0000x reference)
//
#include <hip/hip_runtime.h>

#define BB 4
#define TT 2048
#define CC 1024
#define HH 16
#define DD 64
#define WIN 256

typedef __attribute__((ext_vector_type(8))) short short8;
typedef __attribute__((ext_vector_type(4))) float floatx4;
typedef unsigned short u16;

typedef __attribute__((address_space(3))) void lds_void;
typedef const __attribute__((address_space(1))) void g_void;

__device__ __forceinline__ void gl_lds16(const u16* g, u16* l) {
    // async DMA global->LDS, 16B/lane; LDS dst = wave-uniform base + lane*16
    __builtin_amdgcn_global_load_lds((g_void*)g, (lds_void*)l, 16, 0, 0);
}

__device__ __forceinline__ float bf2f(u16 u) {
    union { unsigned int i; float f; } v; v.i = ((unsigned int)u) << 16; return v.f;
}
__device__ __forceinline__ u16 f2bf(float f) {
    union { float f; unsigned int i; } v; v.f = f;
    unsigned int x = v.i;
    x += ((x >> 16) & 1u) + 0x7FFFu;   // round-to-nearest-even
    return (u16)(x >> 16);
}

// ---------------- fp32 -> bf16 conversion (all three arrays, one launch) -----
__global__ void cvt_all(const float* __restrict__ x, const float* __restrict__ qw,
                        const float* __restrict__ pw,
                        u16* __restrict__ xb, u16* __restrict__ wb, u16* __restrict__ pwb) {
    int bid = blockIdx.x;
    const float* src; u16* dst; int off;
    if (bid < 4096)      { src = x;  dst = xb;  off = bid; }
    else if (bid < 5632) { src = qw; dst = wb;  off = bid - 4096; }
    else                 { src = pw; dst = pwb; off = bid - 5632; }
    int i = (off * 256 + (int)threadIdx.x) * 8;
    float4 a = *(const float4*)(src + i);
    float4 b = *(const float4*)(src + i + 4);
    u16 o[8] = { f2bf(a.x), f2bf(a.y), f2bf(a.z), f2bf(a.w),
                 f2bf(b.x), f2bf(b.y), f2bf(b.z), f2bf(b.w) };
    *(uint4*)(dst + i) = *(const uint4*)o;
}

// ---------------- bf16 MFMA GEMM: C = A @ B^T (+bias), QKV scatter epilogue ----
// Q,K stored [bh][t][d]; V stored TRANSPOSED [bh][d][t] for attention PV.
__global__ __launch_bounds__(256) void gemm_qkv(
    const u16* __restrict__ A, const u16* __restrict__ Bw,
    const float* __restrict__ bias,
    u16* __restrict__ Qb, u16* __restrict__ Kb, u16* __restrict__ Vtg)
{
    const int K = CC;
    __shared__ u16 As[4096];   // 8 KB unpadded, swizzled
    __shared__ u16 Bs[4096];
    const int tid = threadIdx.x;
    const int wave = tid >> 6, lane = tid & 63;
    const int wm = wave >> 1, wn = wave & 1;
    const int quad = lane >> 4, l15 = lane & 15;
    const int bN = blockIdx.x * 128, bM = blockIdx.y * 128;

    const int srow0 = wave * 16 + (lane >> 2);
    const int srow1 = (wave + 4) * 16 + (lane >> 2);
    const int schunk = ((lane & 3) ^ ((lane >> 3) & 3)) * 8;
    const u16* gA0 = A + (size_t)(bM + srow0) * K + schunk;
    const u16* gA1 = A + (size_t)(bM + srow1) * K + schunk;
    const u16* gB0 = Bw + (size_t)(bN + srow0) * K + schunk;
    const u16* gB1 = Bw + (size_t)(bN + srow1) * K + schunk;
    u16* lA0 = &As[wave * 512];
    u16* lA1 = &As[(wave + 4) * 512];
    u16* lB0 = &Bs[wave * 512];
    u16* lB1 = &Bs[(wave + 4) * 512];

    const int rdoff = l15 * 32 + ((quad ^ ((l15 >> 1) & 3)) * 8);  // u16 units

    floatx4 acc[4][4] = {};

    for (int k0 = 0; k0 < K; k0 += 32) {
        __syncthreads();
        gl_lds16(gA0 + k0, lA0);
        gl_lds16(gA1 + k0, lA1);
        gl_lds16(gB0 + k0, lB0);
        gl_lds16(gB1 + k0, lB1);
        __syncthreads();
        short8 af[4], bf[4];
#pragma unroll
        for (int i = 0; i < 4; ++i) {
            af[i] = *(const short8*)&As[(wm * 4 + i) * 512 + rdoff];
            bf[i] = *(const short8*)&Bs[(wn * 4 + i) * 512 + rdoff];
        }
#pragma unroll
        for (int mi = 0; mi < 4; ++mi)
#pragma unroll
            for (int ni = 0; ni < 4; ++ni)
                acc[mi][ni] = __builtin_amdgcn_mfma_f32_16x16x32_bf16(af[mi], bf[ni], acc[mi][ni], 0, 0, 0);
    }

#pragma unroll
    for (int mi = 0; mi < 4; ++mi)
#pragma unroll
        for (int ni = 0; ni < 4; ++ni) {
            int col = bN + wn * 64 + ni * 16 + l15;          // 0..3071 (which is frag-uniform)
            float bv = bias[col];
            int which = col >> 10, rem = col & 1023;
            int h = rem >> 6, d = rem & 63;
            int row0 = bM + wm * 64 + mi * 16 + quad * 4;    // 4 consecutive rows
            int b = row0 >> 11, t0 = row0 & 2047;
            if (which == 2) {
                // V^T: [bh][d][t], 4 consecutive t -> packed b64 store
                u16 pk[4];
#pragma unroll
                for (int rg = 0; rg < 4; ++rg) pk[rg] = f2bf(acc[mi][ni][rg] + bv);
                *(uint2*)&Vtg[(((size_t)(b * HH + h)) * DD + d) * TT + t0] = *(const uint2*)pk;
            } else {
                u16* dst = which == 0 ? Qb : Kb;
#pragma unroll
                for (int rg = 0; rg < 4; ++rg)
                    dst[(((size_t)(b * HH + h)) * TT + t0 + rg) * DD + d] = f2bf(acc[mi][ni][rg] + bv);
            }
        }
}

// ---------------- bf16 MFMA GEMM: Out = A @ B^T + bias (fp32 out) ------------
__global__ __launch_bounds__(256) void gemm_proj(
    const u16* __restrict__ A, const u16* __restrict__ Bw,
    const float* __restrict__ bias, float* __restrict__ Out)
{
    const int K = CC;
    __shared__ u16 As[4096];
    __shared__ u16 Bs[4096];
    const int tid = threadIdx.x;
    const int wave = tid >> 6, lane = tid & 63;
    const int wm = wave >> 1, wn = wave & 1;
    const int quad = lane >> 4, l15 = lane & 15;
    const int bN = blockIdx.x * 128, bM = blockIdx.y * 128;

    const int srow0 = wave * 16 + (lane >> 2);
    const int srow1 = (wave + 4) * 16 + (lane >> 2);
    const int schunk = ((lane & 3) ^ ((lane >> 3) & 3)) * 8;
    const u16* gA0 = A + (size_t)(bM + srow0) * K + schunk;
    const u16* gA1 = A + (size_t)(bM + srow1) * K + schunk;
    const u16* gB0 = Bw + (size_t)(bN + srow0) * K + schunk;
    const u16* gB1 = Bw + (size_t)(bN + srow1) * K + schunk;
    u16* lA0 = &As[wave * 512];
    u16* lA1 = &As[(wave + 4) * 512];
    u16* lB0 = &Bs[wave * 512];
    u16* lB1 = &Bs[(wave + 4) * 512];

    const int rdoff = l15 * 32 + ((quad ^ ((l15 >> 1) & 3)) * 8);

    floatx4 acc[4][4] = {};

    for (int k0 = 0; k0 < K; k0 += 32) {
        __syncthreads();
        gl_lds16(gA0 + k0, lA0);
        gl_lds16(gA1 + k0, lA1);
        gl_lds16(gB0 + k0, lB0);
        gl_lds16(gB1 + k0, lB1);
        __syncthreads();
        short8 af[4], bf[4];
#pragma unroll
        for (int i = 0; i < 4; ++i) {
            af[i] = *(const short8*)&As[(wm * 4 + i) * 512 + rdoff];
            bf[i] = *(const short8*)&Bs[(wn * 4 + i) * 512 + rdoff];
        }
#pragma unroll
        for (int mi = 0; mi < 4; ++mi)
#pragma unroll
            for (int ni = 0; ni < 4; ++ni)
                acc[mi][ni] = __builtin_amdgcn_mfma_f32_16x16x32_bf16(af[mi], bf[ni], acc[mi][ni], 0, 0, 0);
    }

#pragma unroll
    for (int mi = 0; mi < 4; ++mi)
#pragma unroll
        for (int ni = 0; ni < 4; ++ni) {
            int col = bN + wn * 64 + ni * 16 + l15;
            float bv = bias[col];
#pragma unroll
            for (int rg = 0; rg < 4; ++rg) {
                int row = bM + wm * 64 + mi * 16 + quad * 4 + rg;
                Out[(size_t)row * CC + col] = acc[mi][ni][rg] + bv;
            }
        }
}

// ---------------- flash attention, transposed-S MFMA -------------------------
// Q,K: [bh][t][d]; Vtg: [bh][d][t] (transposed).  Y: [B,T,C] bf16.
// S^T = K Q^T (A=K natural, B=Q registers)  -> C layout: row=j, col=q=lane&15
// O^T = V^T P (A=V^T natural, B=P from LDS) -> C layout: row=d, col=q=lane&15
// => softmax state m,l,alpha is ONE scalar per lane; reductions = 2 shuffles.
__global__ __launch_bounds__(256) void attn_mfma(
    const u16* __restrict__ Qb, const u16* __restrict__ Kb, const u16* __restrict__ Vtg,
    u16* __restrict__ Y)
{
    __shared__ __align__(16) u16 Ks[4096];        // [j][d] 64x64, chunk-swizzled
    __shared__ __align__(16) u16 Vs[4096];        // [d][j] 64x64, chunk-swizzled
    __shared__ __align__(16) u16 Ps[4][16][72];   // [wave][q][j], +8 pad

    const int tid = threadIdx.x;
    const int wave = tid >> 6, lane = tid & 63;
    const int quad = lane >> 4, l15 = lane & 15;
    const int q0 = blockIdx.x * 64;
    const int bh = blockIdx.y;
    const int b = bh >> 4, h = bh & 15;
    const u16* Qp = Qb + (size_t)bh * TT * DD;
    const u16* Kp = Kb + (size_t)bh * TT * DD;
    const u16* Vp = Vtg + (size_t)bh * DD * TT;   // [d][T]
    const int qw = q0 + wave * 16;

    // DMA source addressing: lane L -> LDS (seg*1024 + L*16). Row = seg*8+(L>>3),
    // position p=L&7 must hold global chunk c = p ^ (row&7).
    const int lrow = lane >> 3;                       // 0..7
    const int lchunk = ((lane & 7) ^ lrow) << 3;      // u16 offset of global 16B chunk
    const int s0 = wave * 2, s1 = wave * 2 + 1;

    // Q B-fragments (register-resident): B[n=q=l15][k=d]
    short8 qf[2];
    qf[0] = *(const short8*)&Qp[(size_t)(qw + l15) * DD + quad * 8];
    qf[1] = *(const short8*)&Qp[(size_t)(qw + l15) * DD + 32 + quad * 8];

    float m_i = -1e30f, l_i = 0.f;
    floatx4 Oacc[4] = {};   // O^T: [dt] row d=dt*16+quad*4+r, col q=l15

    const int swz = l15 & 7;
    const int kb = (q0 >= WIN) ? (q0 - WIN) : 0;
    for (int j0 = kb; j0 < q0 + 64; j0 += 64) {
        __syncthreads();
        gl_lds16(&Kp[(size_t)(j0 + s0 * 8 + lrow) * DD + lchunk], &Ks[s0 * 512]);
        gl_lds16(&Kp[(size_t)(j0 + s1 * 8 + lrow) * DD + lchunk], &Ks[s1 * 512]);
        gl_lds16(&Vp[(size_t)(s0 * 8 + lrow) * TT + j0 + lchunk], &Vs[s0 * 512]);
        gl_lds16(&Vp[(size_t)(s1 * 8 + lrow) * TT + j0 + lchunk], &Vs[s1 * 512]);
        __syncthreads();

        // ---- S^T = K Q^T: 4 key m-tiles x 2 k-steps ----
        floatx4 Sacc[4] = {};
#pragma unroll
        for (int ks = 0; ks < 2; ++ks)
#pragma unroll
            for (int kt = 0; kt < 4; ++kt) {
                short8 kf = *(const short8*)&Ks[(kt * 16 + l15) * 64 + (((ks * 4 + quad) ^ swz) << 3)];
                Sacc[kt] = __builtin_amdgcn_mfma_f32_16x16x32_bf16(kf, qf[ks], Sacc[kt], 0, 0, 0);
            }

        // ---- mask + scale + chunk max (per-lane scalar state!) ----
        const int q = qw + l15;
        float mc = -1e30f;
#pragma unroll
        for (int kt = 0; kt < 4; ++kt)
#pragma unroll
            for (int r = 0; r < 4; ++r) {
                int j = j0 + kt * 16 + quad * 4 + r;
                float s = (j <= q && (q - j) < WIN) ? Sacc[kt][r] * 0.125f : -1e30f;
                Sacc[kt][r] = s;
                mc = fmaxf(mc, s);
            }
        mc = fmaxf(mc, __shfl_xor(mc, 16, 64));
        mc = fmaxf(mc, __shfl_xor(mc, 32, 64));

        float mn = fmaxf(m_i, mc);
        float alpha = __expf(m_i - mn);
        m_i = mn;

        float rs = 0.f;
#pragma unroll
        for (int kt = 0; kt < 4; ++kt) {
            u16 pk[4];
#pragma unroll
            for (int r = 0; r < 4; ++r) {
                float s = Sacc[kt][r];
                float p = (s > -1e29f) ? __expf(s - m_i) : 0.f;
                rs += p;
                pk[r] = f2bf(p);
            }
            // P[q][j]: b64-packed write (4 consecutive j)
            *(uint2*)&Ps[wave][l15][kt * 16 + quad * 4] = *(const uint2*)pk;
        }
        rs += __shfl_xor(rs, 16, 64);
        rs += __shfl_xor(rs, 32, 64);
        l_i = l_i * alpha + rs;
#pragma unroll
        for (int dt = 0; dt < 4; ++dt)
#pragma unroll
            for (int r = 0; r < 4; ++r) Oacc[dt][r] *= alpha;

        // ---- O^T += V^T P ----
#pragma unroll
        for (int ks = 0; ks < 2; ++ks) {
            short8 pf = *(const short8*)&Ps[wave][l15][ks * 32 + quad * 8];
#pragma unroll
            for (int dt = 0; dt < 4; ++dt) {
                short8 vf = *(const short8*)&Vs[(dt * 16 + l15) * 64 + (((ks * 4 + quad) ^ swz) << 3)];
                Oacc[dt] = __builtin_amdgcn_mfma_f32_16x16x32_bf16(vf, pf, Oacc[dt], 0, 0, 0);
            }
        }
    }

    // ---- epilogue: O^T/l -> Y[b, t=qw+l15, h*64 + d], b64-packed ----
    float inv = 1.f / l_i;
    const int t = qw + l15;
#pragma unroll
    for (int dt = 0; dt < 4; ++dt) {
        u16 o[4];
#pragma unroll
        for (int r = 0; r < 4; ++r) o[r] = f2bf(Oacc[dt][r] * inv);
        *(uint2*)&Y[((size_t)b * TT + t) * CC + h * DD + dt * 16 + quad * 4] = *(const uint2*)o;
    }
}

// ---------------- launch ----------------
extern "C" void kernel_launch(void* const* d_in, const int* in_sizes, int n_in,
                              void* d_out, int out_size, void* d_ws, size_t ws_size,
                              hipStream_t stream) {
    const float* x      = (const float*)d_in[0];
    // d_in[1] = attn_mask (bool) — mask structure is analytic, unused
    const float* qkv_w  = (const float*)d_in[2];
    const float* qkv_b  = (const float*)d_in[3];
    const float* proj_w = (const float*)d_in[4];
    const float* proj_b = (const float*)d_in[5];
    float* out = (float*)d_out;

    u16* xb  = (u16*)d_ws;                         // 8192*1024
    u16* wb  = xb  + (size_t)8192 * 1024;          // 3072*1024
    u16* pwb = wb  + (size_t)3072 * 1024;          // 1024*1024
    u16* Qb  = pwb + (size_t)1024 * 1024;          // [bh][t][d]
    u16* Kb  = Qb  + (size_t)64 * 2048 * 64;       // [bh][t][d]
    u16* Vtg = Kb  + (size_t)64 * 2048 * 64;       // [bh][d][t]  (transposed)
    u16* Yb  = Vtg + (size_t)64 * 2048 * 64;       // 8192*1024

    cvt_all<<<6144, 256, 0, stream>>>(x, qkv_w, proj_w, xb, wb, pwb);
    gemm_qkv<<<dim3(24, 64), 256, 0, stream>>>(xb, wb, qkv_b, Qb, Kb, Vtg);
    attn_mfma<<<dim3(TT / 64, BB * HH), 256, 0, stream>>>(Qb, Kb, Vtg, Yb);
    gemm_proj<<<dim3(8, 64), 256, 0, stream>>>(Yb, pwb, proj_b, out);
}

// Round 5
// 241.365 us; speedup vs baseline: 1.0119x; 1.0119x over previous
//
#include <hip/hip_runtime.h>

#define BB 4
#define TT 2048
#define CC 1024
#define HH 16
#define DD 64
#define WIN 256

typedef __attribute__((ext_vector_type(8))) short short8;
typedef __attribute__((ext_vector_type(4))) float floatx4;
typedef unsigned short u16;

typedef __attribute__((address_space(3))) void lds_void;
typedef const __attribute__((address_space(1))) void g_void;

__device__ __forceinline__ void gl_lds16(const u16* g, u16* l) {
    // async DMA global->LDS, 16B/lane; LDS dst = wave-uniform base + lane*16
    __builtin_amdgcn_global_load_lds((g_void*)g, (lds_void*)l, 16, 0, 0);
}

__device__ __forceinline__ float bf2f(u16 u) {
    union { unsigned int i; float f; } v; v.i = ((unsigned int)u) << 16; return v.f;
}
__device__ __forceinline__ u16 f2bf(float f) {
    union { float f; unsigned int i; } v; v.f = f;
    unsigned int x = v.i;
    x += ((x >> 16) & 1u) + 0x7FFFu;   // round-to-nearest-even
    return (u16)(x >> 16);
}

// ---------------- fp32 -> bf16 conversion (all three arrays, one launch) -----
__global__ void cvt_all(const float* __restrict__ x, const float* __restrict__ qw,
                        const float* __restrict__ pw,
                        u16* __restrict__ xb, u16* __restrict__ wb, u16* __restrict__ pwb) {
    int bid = blockIdx.x;
    const float* src; u16* dst; int off;
    if (bid < 4096)      { src = x;  dst = xb;  off = bid; }
    else if (bid < 5632) { src = qw; dst = wb;  off = bid - 4096; }
    else                 { src = pw; dst = pwb; off = bid - 5632; }
    int i = (off * 256 + (int)threadIdx.x) * 8;
    float4 a = *(const float4*)(src + i);
    float4 b = *(const float4*)(src + i + 4);
    u16 o[8] = { f2bf(a.x), f2bf(a.y), f2bf(a.z), f2bf(a.w),
                 f2bf(b.x), f2bf(b.y), f2bf(b.z), f2bf(b.w) };
    *(uint4*)(dst + i) = *(const uint4*)o;
}

// ---------------- bf16 MFMA GEMM: C = A @ B^T (+bias), QKV scatter epilogue ----
// Q,K stored [bh][t][d]; V stored TRANSPOSED [bh][d][t].
// V-owning blocks (bN>=2048) swap MFMA operands so acc holds C^T directly:
// identical instruction/register cost, coalesced V^T stores (lanes = consecutive t).
__global__ __launch_bounds__(256) void gemm_qkv(
    const u16* __restrict__ A, const u16* __restrict__ Bw,
    const float* __restrict__ bias,
    u16* __restrict__ Qb, u16* __restrict__ Kb, u16* __restrict__ Vtg)
{
    const int K = CC;
    __shared__ u16 As[4096];   // 8 KB unpadded, swizzled
    __shared__ u16 Bs[4096];
    const int tid = threadIdx.x;
    const int wave = tid >> 6, lane = tid & 63;
    const int wm = wave >> 1, wn = wave & 1;
    const int quad = lane >> 4, l15 = lane & 15;
    const int bN = blockIdx.x * 128, bM = blockIdx.y * 128;
    const bool isV = (bN >= 2048);

    const int srow0 = wave * 16 + (lane >> 2);
    const int srow1 = (wave + 4) * 16 + (lane >> 2);
    const int schunk = ((lane & 3) ^ ((lane >> 3) & 3)) * 8;
    const u16* gA0 = A + (size_t)(bM + srow0) * K + schunk;
    const u16* gA1 = A + (size_t)(bM + srow1) * K + schunk;
    const u16* gB0 = Bw + (size_t)(bN + srow0) * K + schunk;
    const u16* gB1 = Bw + (size_t)(bN + srow1) * K + schunk;
    u16* lA0 = &As[wave * 512];
    u16* lA1 = &As[(wave + 4) * 512];
    u16* lB0 = &Bs[wave * 512];
    u16* lB1 = &Bs[(wave + 4) * 512];

    const int rdoff = l15 * 32 + ((quad ^ ((l15 >> 1) & 3)) * 8);  // u16 units

    floatx4 acc[4][4] = {};

    if (!isV) {
        for (int k0 = 0; k0 < K; k0 += 32) {
            __syncthreads();
            gl_lds16(gA0 + k0, lA0);
            gl_lds16(gA1 + k0, lA1);
            gl_lds16(gB0 + k0, lB0);
            gl_lds16(gB1 + k0, lB1);
            __syncthreads();
            short8 af[4], bf[4];
#pragma unroll
            for (int i = 0; i < 4; ++i) {
                af[i] = *(const short8*)&As[(wm * 4 + i) * 512 + rdoff];
                bf[i] = *(const short8*)&Bs[(wn * 4 + i) * 512 + rdoff];
            }
#pragma unroll
            for (int mi = 0; mi < 4; ++mi)
#pragma unroll
                for (int ni = 0; ni < 4; ++ni)
                    acc[mi][ni] = __builtin_amdgcn_mfma_f32_16x16x32_bf16(af[mi], bf[ni], acc[mi][ni], 0, 0, 0);
        }
        // ---- Q/K epilogue: C layout row=t(quad*4+rg), col=l15 ----
#pragma unroll
        for (int mi = 0; mi < 4; ++mi)
#pragma unroll
            for (int ni = 0; ni < 4; ++ni) {
                int col = bN + wn * 64 + ni * 16 + l15;
                float bv = bias[col];
                int which = col >> 10, rem = col & 1023;
                int h = rem >> 6, d = rem & 63;
                int row0 = bM + wm * 64 + mi * 16 + quad * 4;
                int b = row0 >> 11, t0 = row0 & 2047;
                u16* dst = which == 0 ? Qb : Kb;
#pragma unroll
                for (int rg = 0; rg < 4; ++rg)
                    dst[(((size_t)(b * HH + h)) * TT + t0 + rg) * DD + d] = f2bf(acc[mi][ni][rg] + bv);
            }
    } else {
        for (int k0 = 0; k0 < K; k0 += 32) {
            __syncthreads();
            gl_lds16(gA0 + k0, lA0);
            gl_lds16(gA1 + k0, lA1);
            gl_lds16(gB0 + k0, lB0);
            gl_lds16(gB1 + k0, lB1);
            __syncthreads();
            short8 af[4], bf[4];
#pragma unroll
            for (int i = 0; i < 4; ++i) {
                af[i] = *(const short8*)&As[(wm * 4 + i) * 512 + rdoff];
                bf[i] = *(const short8*)&Bs[(wn * 4 + i) * 512 + rdoff];
            }
#pragma unroll
            for (int mi = 0; mi < 4; ++mi)
#pragma unroll
                for (int ni = 0; ni < 4; ++ni)   // SWAPPED: acc = C^T fragment
                    acc[mi][ni] = __builtin_amdgcn_mfma_f32_16x16x32_bf16(bf[ni], af[mi], acc[mi][ni], 0, 0, 0);
        }
        // ---- V^T epilogue: C^T layout row=qkv-col(quad*4+rg), col-lane=t(l15) ----
#pragma unroll
        for (int mi = 0; mi < 4; ++mi)
#pragma unroll
            for (int ni = 0; ni < 4; ++ni) {
                int col0 = bN + wn * 64 + ni * 16 + quad * 4;   // 4 consecutive qkv cols
                int row = bM + wm * 64 + mi * 16 + l15;          // token (lanes consecutive)
                int b = row >> 11, t = row & 2047;
#pragma unroll
                for (int rg = 0; rg < 4; ++rg) {
                    int c = col0 + rg;
                    int h = (c & 1023) >> 6, d = c & 63;
                    float v = acc[mi][ni][rg] + bias[c];
                    Vtg[(((size_t)(b * HH + h)) * DD + d) * TT + t] = f2bf(v);
                }
            }
    }
}

// ---------------- bf16 MFMA GEMM: Out = A @ B^T + bias (fp32 out) ------------
__global__ __launch_bounds__(256) void gemm_proj(
    const u16* __restrict__ A, const u16* __restrict__ Bw,
    const float* __restrict__ bias, float* __restrict__ Out)
{
    const int K = CC;
    __shared__ u16 As[4096];
    __shared__ u16 Bs[4096];
    const int tid = threadIdx.x;
    const int wave = tid >> 6, lane = tid & 63;
    const int wm = wave >> 1, wn = wave & 1;
    const int quad = lane >> 4, l15 = lane & 15;
    const int bN = blockIdx.x * 128, bM = blockIdx.y * 128;

    const int srow0 = wave * 16 + (lane >> 2);
    const int srow1 = (wave + 4) * 16 + (lane >> 2);
    const int schunk = ((lane & 3) ^ ((lane >> 3) & 3)) * 8;
    const u16* gA0 = A + (size_t)(bM + srow0) * K + schunk;
    const u16* gA1 = A + (size_t)(bM + srow1) * K + schunk;
    const u16* gB0 = Bw + (size_t)(bN + srow0) * K + schunk;
    const u16* gB1 = Bw + (size_t)(bN + srow1) * K + schunk;
    u16* lA0 = &As[wave * 512];
    u16* lA1 = &As[(wave + 4) * 512];
    u16* lB0 = &Bs[wave * 512];
    u16* lB1 = &Bs[(wave + 4) * 512];

    const int rdoff = l15 * 32 + ((quad ^ ((l15 >> 1) & 3)) * 8);

    floatx4 acc[4][4] = {};

    for (int k0 = 0; k0 < K; k0 += 32) {
        __syncthreads();
        gl_lds16(gA0 + k0, lA0);
        gl_lds16(gA1 + k0, lA1);
        gl_lds16(gB0 + k0, lB0);
        gl_lds16(gB1 + k0, lB1);
        __syncthreads();
        short8 af[4], bf[4];
#pragma unroll
        for (int i = 0; i < 4; ++i) {
            af[i] = *(const short8*)&As[(wm * 4 + i) * 512 + rdoff];
            bf[i] = *(const short8*)&Bs[(wn * 4 + i) * 512 + rdoff];
        }
#pragma unroll
        for (int mi = 0; mi < 4; ++mi)
#pragma unroll
            for (int ni = 0; ni < 4; ++ni)
                acc[mi][ni] = __builtin_amdgcn_mfma_f32_16x16x32_bf16(af[mi], bf[ni], acc[mi][ni], 0, 0, 0);
    }

#pragma unroll
    for (int mi = 0; mi < 4; ++mi)
#pragma unroll
        for (int ni = 0; ni < 4; ++ni) {
            int col = bN + wn * 64 + ni * 16 + l15;
            float bv = bias[col];
#pragma unroll
            for (int rg = 0; rg < 4; ++rg) {
                int row = bM + wm * 64 + mi * 16 + quad * 4 + rg;
                Out[(size_t)row * CC + col] = acc[mi][ni][rg] + bv;
            }
        }
}

// ---------------- flash attention, transposed-S MFMA -------------------------
// Q,K: [bh][t][d]; Vtg: [bh][d][t] (transposed).  Y: [B,T,C] bf16.
// S^T = K Q^T (A=K natural, B=Q registers)  -> C layout: row=j, col=q=lane&15
// O^T = V^T P (A=V^T natural, B=P from LDS) -> C layout: row=d, col=q=lane&15
// => softmax state m,l,alpha is ONE scalar per lane; reductions = 2 shuffles.
__global__ __launch_bounds__(256) void attn_mfma(
    const u16* __restrict__ Qb, const u16* __restrict__ Kb, const u16* __restrict__ Vtg,
    u16* __restrict__ Y)
{
    __shared__ __align__(16) u16 Ks[4096];        // [j][d] 64x64, chunk-swizzled
    __shared__ __align__(16) u16 Vs[4096];        // [d][j] 64x64, chunk-swizzled
    __shared__ __align__(16) u16 Ps[4][16][72];   // [wave][q][j], +8 pad

    const int tid = threadIdx.x;
    const int wave = tid >> 6, lane = tid & 63;
    const int quad = lane >> 4, l15 = lane & 15;
    const int q0 = blockIdx.x * 64;
    const int bh = blockIdx.y;
    const int b = bh >> 4, h = bh & 15;
    const u16* Qp = Qb + (size_t)bh * TT * DD;
    const u16* Kp = Kb + (size_t)bh * TT * DD;
    const u16* Vp = Vtg + (size_t)bh * DD * TT;   // [d][T]
    const int qw = q0 + wave * 16;

    // DMA source addressing: lane L -> LDS (seg*1024 + L*16). Row = seg*8+(L>>3),
    // position p=L&7 must hold global chunk c = p ^ (row&7).
    const int lrow = lane >> 3;                       // 0..7
    const int lchunk = ((lane & 7) ^ lrow) << 3;      // u16 offset of global 16B chunk
    const int s0 = wave * 2, s1 = wave * 2 + 1;

    // Q B-fragments (register-resident): B[n=q=l15][k=d]
    short8 qf[2];
    qf[0] = *(const short8*)&Qp[(size_t)(qw + l15) * DD + quad * 8];
    qf[1] = *(const short8*)&Qp[(size_t)(qw + l15) * DD + 32 + quad * 8];

    float m_i = -1e30f, l_i = 0.f;
    floatx4 Oacc[4] = {};   // O^T: [dt] row d=dt*16+quad*4+r, col q=l15

    const int swz = l15 & 7;
    const int kb = (q0 >= WIN) ? (q0 - WIN) : 0;
    for (int j0 = kb; j0 < q0 + 64; j0 += 64) {
        __syncthreads();
        gl_lds16(&Kp[(size_t)(j0 + s0 * 8 + lrow) * DD + lchunk], &Ks[s0 * 512]);
        gl_lds16(&Kp[(size_t)(j0 + s1 * 8 + lrow) * DD + lchunk], &Ks[s1 * 512]);
        gl_lds16(&Vp[(size_t)(s0 * 8 + lrow) * TT + j0 + lchunk], &Vs[s0 * 512]);
        gl_lds16(&Vp[(size_t)(s1 * 8 + lrow) * TT + j0 + lchunk], &Vs[s1 * 512]);
        __syncthreads();

        // ---- S^T = K Q^T: 4 key m-tiles x 2 k-steps ----
        floatx4 Sacc[4] = {};
#pragma unroll
        for (int ks = 0; ks < 2; ++ks)
#pragma unroll
            for (int kt = 0; kt < 4; ++kt) {
                short8 kf = *(const short8*)&Ks[(kt * 16 + l15) * 64 + (((ks * 4 + quad) ^ swz) << 3)];
                Sacc[kt] = __builtin_amdgcn_mfma_f32_16x16x32_bf16(kf, qf[ks], Sacc[kt], 0, 0, 0);
            }

        // ---- mask + scale + chunk max (per-lane scalar state!) ----
        const int q = qw + l15;
        float mc = -1e30f;
#pragma unroll
        for (int kt = 0; kt < 4; ++kt)
#pragma unroll
            for (int r = 0; r < 4; ++r) {
                int j = j0 + kt * 16 + quad * 4 + r;
                float s = (j <= q && (q - j) < WIN) ? Sacc[kt][r] * 0.125f : -1e30f;
                Sacc[kt][r] = s;
                mc = fmaxf(mc, s);
            }
        mc = fmaxf(mc, __shfl_xor(mc, 16, 64));
        mc = fmaxf(mc, __shfl_xor(mc, 32, 64));

        float mn = fmaxf(m_i, mc);
        float alpha = __expf(m_i - mn);
        m_i = mn;

        float rs = 0.f;
#pragma unroll
        for (int kt = 0; kt < 4; ++kt) {
            u16 pk[4];
#pragma unroll
            for (int r = 0; r < 4; ++r) {
                float s = Sacc[kt][r];
                float p = (s > -1e29f) ? __expf(s - m_i) : 0.f;
                rs += p;
                pk[r] = f2bf(p);
            }
            // P[q][j]: b64-packed write (4 consecutive j)
            *(uint2*)&Ps[wave][l15][kt * 16 + quad * 4] = *(const uint2*)pk;
        }
        rs += __shfl_xor(rs, 16, 64);
        rs += __shfl_xor(rs, 32, 64);
        l_i = l_i * alpha + rs;
#pragma unroll
        for (int dt = 0; dt < 4; ++dt)
#pragma unroll
            for (int r = 0; r < 4; ++r) Oacc[dt][r] *= alpha;

        // ---- O^T += V^T P ----
#pragma unroll
        for (int ks = 0; ks < 2; ++ks) {
            short8 pf = *(const short8*)&Ps[wave][l15][ks * 32 + quad * 8];
#pragma unroll
            for (int dt = 0; dt < 4; ++dt) {
                short8 vf = *(const short8*)&Vs[(dt * 16 + l15) * 64 + (((ks * 4 + quad) ^ swz) << 3)];
                Oacc[dt] = __builtin_amdgcn_mfma_f32_16x16x32_bf16(vf, pf, Oacc[dt], 0, 0, 0);
            }
        }
    }

    // ---- epilogue: O^T/l -> Y[b, t=qw+l15, h*64 + d], b64-packed ----
    float inv = 1.f / l_i;
    const int t = qw + l15;
#pragma unroll
    for (int dt = 0; dt < 4; ++dt) {
        u16 o[4];
#pragma unroll
        for (int r = 0; r < 4; ++r) o[r] = f2bf(Oacc[dt][r] * inv);
        *(uint2*)&Y[((size_t)b * TT + t) * CC + h * DD + dt * 16 + quad * 4] = *(const uint2*)o;
    }
}

// ---------------- launch ----------------
extern "C" void kernel_launch(void* const* d_in, const int* in_sizes, int n_in,
                              void* d_out, int out_size, void* d_ws, size_t ws_size,
                              hipStream_t stream) {
    const float* x      = (const float*)d_in[0];
    // d_in[1] = attn_mask (bool) — mask structure is analytic, unused
    const float* qkv_w  = (const float*)d_in[2];
    const float* qkv_b  = (const float*)d_in[3];
    const float* proj_w = (const float*)d_in[4];
    const float* proj_b = (const float*)d_in[5];
    float* out = (float*)d_out;

    u16* xb  = (u16*)d_ws;                         // 8192*1024
    u16* wb  = xb  + (size_t)8192 * 1024;          // 3072*1024
    u16* pwb = wb  + (size_t)3072 * 1024;          // 1024*1024
    u16* Qb  = pwb + (size_t)1024 * 1024;          // [bh][t][d]
    u16* Kb  = Qb  + (size_t)64 * 2048 * 64;       // [bh][t][d]
    u16* Vtg = Kb  + (size_t)64 * 2048 * 64;       // [bh][d][t]  (transposed)
    u16* Yb  = Vtg + (size_t)64 * 2048 * 64;       // 8192*1024

    cvt_all<<<6144, 256, 0, stream>>>(x, qkv_w, proj_w, xb, wb, pwb);
    gemm_qkv<<<dim3(24, 64), 256, 0, stream>>>(xb, wb, qkv_b, Qb, Kb, Vtg);
    attn_mfma<<<dim3(TT / 64, BB * HH), 256, 0, stream>>>(Qb, Kb, Vtg, Yb);
    gemm_proj<<<dim3(8, 64), 256, 0, stream>>>(Yb, pwb, proj_b, out);
}